// Round 13
// baseline (172.739 us; speedup 1.0000x reference)
//
#include <hip/hip_runtime.h>
#include <hip/hip_bf16.h>

#define DD   512
#define NH   32
#define AA   18
#define JJ   (NH*AA)          // 576
#define BB   4096
#define JD   (JJ*DD)          // 294912
#define MAGICW 0x7E57C0DEu

typedef short bf16x8 __attribute__((ext_vector_type(8)));
typedef float f32x4  __attribute__((ext_vector_type(4)));

static __device__ inline unsigned short f2bf(float f) {
    unsigned int x = __float_as_uint(f);
    unsigned int r = (x + 0x7fffu + ((x >> 16) & 1u)) >> 16;   // RNE
    return (unsigned short)r;
}
static __device__ inline float bf2f(unsigned short bits) {
    return __uint_as_float((unsigned int)bits << 16);
}

#define GBM 128
#define GBN 64
#define GBK 64

// ---------------------------------------------------------------------------
// Single launch, 512 blocks x 256 thr. Per block (c = blk&15, n = blk>>4):
//   Phase V (R12 k_V verbatim): convX slice + U-stage + c1 + V-chunk MFMA
//     -> threadfence + release m1[blk]
//   Phase M (R12 k_M verbatim): spin on m1[n*16+0..15] -> V-stage + c3 +
//     M-chunk MFMA -> threadfence + release m2[blk]
//   Phase C (R12 k_gemm verbatim, 288 tiles BM=128): spin on 16 conv m1 +
//     heads' m2 -> out tile.
// Flags are MAGIC-valued (no reset needed): stale-magic early pass reads
// bitwise-identical recomputed data (deterministic) -> benign.
// ---------------------------------------------------------------------------
__global__ __launch_bounds__(256) void k_all(
    const float* __restrict__ x,  const float* __restrict__ W1,
    const float* __restrict__ b1, const float* __restrict__ W2,
    const float* __restrict__ b2, const float* __restrict__ Wv,
    const float* __restrict__ bv, const float* __restrict__ Wa,
    const float* __restrict__ ba, float* __restrict__ out,
    unsigned short* __restrict__ Xb, unsigned short* __restrict__ Vb,
    unsigned short* __restrict__ Mb, float* __restrict__ c1,
    float* __restrict__ c3, unsigned* m1, unsigned* m2)
{
    __shared__ __align__(16) unsigned short sbuf[32 * DD];   // 32 KB
    __shared__ float redc[AA * 4];

    const int t   = threadIdx.x;
    const int blk = blockIdx.x;        // 0..511
    const int c   = blk & 15;          // chunk (dc in V, kc in M)
    const int n   = blk >> 4;          // head

    // ===================== Phase V =====================
    {
        unsigned short* usb = sbuf;

        // a) convX slice: block blk owns float4s [blk*1024, blk*1024+1024)
        {
            const float4* xin = (const float4*)x + (size_t)blk*1024;
            ushort4*      xo  = (ushort4*)Xb + (size_t)blk*1024;
            #pragma unroll
            for (int i = 0; i < 4; ++i) {
                const float4 v = xin[t + 256*i];
                ushort4 o;
                o.x = f2bf(v.x); o.y = f2bf(v.y); o.z = f2bf(v.z); o.w = f2bf(v.w);
                xo[t + 256*i] = o;
            }
        }

        // b) stage U bf16 swizzled; c==0 folds c1
        {
            const int e = 2*t;
            float u0[AA], u1[AA];
            float msum0 = 0.f, msum1 = 0.f;
            #pragma unroll
            for (int a = 0; a < AA; ++a) {
                const float2 w = *(const float2*)(Wa + (size_t)(n*AA + a)*DD + e);
                u0[a] = w.x; u1[a] = w.y; msum0 += w.x; msum1 += w.y;
            }
            msum0 *= (1.0f/18.0f); msum1 *= (1.0f/18.0f);
            const float2 wv  = *(const float2*)(Wv + (size_t)n*DD + e);
            const float2 b2v = *(const float2*)(b2 + (size_t)n*DD + e);
            float p[AA];
            #pragma unroll
            for (int a = 0; a < AA; ++a) {
                u0[a] = wv.x + u0[a] - msum0;
                u1[a] = wv.y + u1[a] - msum1;
                const unsigned int pk = ((unsigned int)f2bf(u1[a]) << 16) | f2bf(u0[a]);
                const int slot = (t >> 2) ^ (a & 7);      // 16B-slot swizzle
                *(unsigned int*)(usb + a*DD + slot*8 + (t & 3)*2) = pk;
                p[a] = u0[a]*b2v.x + u1[a]*b2v.y;
            }
            if (c == 0) {   // block-uniform branch
                #pragma unroll
                for (int a = 0; a < AA; ++a)
                    for (int o = 32; o; o >>= 1) p[a] += __shfl_xor(p[a], o, 64);
                if ((t & 63) == 0) {
                    const int w = t >> 6;
                    #pragma unroll
                    for (int a = 0; a < AA; ++a) redc[a*4 + w] = p[a];
                }
                __syncthreads();
                if (t < AA)
                    c1[n*AA + t] = redc[t*4] + redc[t*4+1] + redc[t*4+2] + redc[t*4+3];
            }
        }
        __syncthreads();

        // c) MFMA contraction over e
        const int lane = t & 63, w = t >> 6;
        const int wp = w & 1;
        const int wd = w >> 1;
        const int ln = lane & 15, lg = lane >> 4;
        const int d0 = c*32 + wd*16;
        const int arow = wp*16 + ln;
        const float* w2base = W2 + (size_t)n*DD*DD + d0 + ln;

        f32x4 acc = {};
        #pragma unroll 2
        for (int kt = 0; kt < 16; ++kt) {
            const float* gp = w2base + (size_t)(kt*32 + lg*8)*DD;
            float wvv[8];
            #pragma unroll
            for (int j = 0; j < 8; ++j) wvv[j] = gp[(size_t)j*DD];
            bf16x8 bfrag;
            #pragma unroll
            for (int j = 0; j < 8; ++j) bfrag[j] = (short)f2bf(wvv[j]);
            const int slot = (kt*4 + lg) ^ (arow & 7);
            const bf16x8 afrag = *(const bf16x8*)(usb + arow*DD + slot*8);
            acc = __builtin_amdgcn_mfma_f32_16x16x32_bf16(afrag, bfrag, acc, 0, 0, 0);
        }

        // D layout: col=lane&15 (d), row=(lane>>4)*4+reg (a)  [m89/m91]
        #pragma unroll
        for (int r = 0; r < 4; ++r) {
            const int a = wp*16 + lg*4 + r;
            if (a < AA)
                Vb[(size_t)(n*AA + a)*DD + d0 + ln] = f2bf(acc[r]);
        }
    }
    // signal V-chunk (and conv slice) done
    __threadfence();
    __syncthreads();
    if (t == 0)
        __hip_atomic_store(&m1[blk], MAGICW, __ATOMIC_RELEASE, __HIP_MEMORY_SCOPE_AGENT);

    // wait for all 16 V-chunks of head n
    if (t < 16)
        while (__hip_atomic_load(&m1[n*16 + t], __ATOMIC_ACQUIRE,
                                 __HIP_MEMORY_SCOPE_AGENT) != MAGICW)
            __builtin_amdgcn_s_sleep(1);
    __syncthreads();

    // ===================== Phase M =====================
    {
        unsigned short* vsb = sbuf;

        // stage V -> LDS swizzled
        for (int idx = t; idx < AA*64; idx += 256) {
            const int row = idx >> 6, slot = idx & 63;
            const int4 v = *(const int4*)(Vb + (size_t)(n*AA + row)*DD + slot*8);
            *(int4*)(vsb + row*DD + ((slot ^ (row & 7))*8)) = v;
        }
        __syncthreads();

        // a) c3 on c==0 blocks
        if (c == 0) {
            const int e = 2*t;
            const float2 b1v = *(const float2*)(b1 + (size_t)n*DD + e);
            float p[AA];
            #pragma unroll
            for (int a = 0; a < AA; ++a) {
                const unsigned int pk = *(const unsigned int*)(Vb + (size_t)(n*AA + a)*DD + e);
                p[a] = bf2f((unsigned short)(pk & 0xffffu))*b1v.x
                     + bf2f((unsigned short)(pk >> 16))*b1v.y;
            }
            #pragma unroll
            for (int a = 0; a < AA; ++a)
                for (int o = 32; o; o >>= 1) p[a] += __shfl_xor(p[a], o, 64);
            if ((t & 63) == 0) {
                const int w = t >> 6;
                #pragma unroll
                for (int a = 0; a < AA; ++a) redc[a*4 + w] = p[a];
            }
            __syncthreads();
            if (t < AA) {
                float bam = 0.f;
                #pragma unroll
                for (int a = 0; a < AA; ++a) bam += ba[n*AA + a];
                c3[n*AA + t] = c1[n*AA + t]
                             + redc[t*4] + redc[t*4+1] + redc[t*4+2] + redc[t*4+3]
                             + bv[n] + ba[n*AA + t] - bam * (1.0f/18.0f);
            }
        }

        // b) MFMA contraction over d
        const int lane = t & 63, w = t >> 6;
        const int wp = w & 1;
        const int wd = w >> 1;
        const int ln = lane & 15, lg = lane >> 4;
        const int k0 = c*32 + wd*16;
        const int arow = wp*16 + ln;
        const float* w1base = W1 + (size_t)n*DD*DD + k0 + ln;

        f32x4 acc = {};
        #pragma unroll 2
        for (int kt = 0; kt < 16; ++kt) {
            const float* gp = w1base + (size_t)(kt*32 + lg*8)*DD;
            float wvv[8];
            #pragma unroll
            for (int j = 0; j < 8; ++j) wvv[j] = gp[(size_t)j*DD];
            bf16x8 bfrag;
            #pragma unroll
            for (int j = 0; j < 8; ++j) bfrag[j] = (short)f2bf(wvv[j]);
            const int slot = (kt*4 + lg) ^ (arow & 7);
            const bf16x8 afrag = *(const bf16x8*)(vsb + arow*DD + slot*8);
            acc = __builtin_amdgcn_mfma_f32_16x16x32_bf16(afrag, bfrag, acc, 0, 0, 0);
        }

        #pragma unroll
        for (int r = 0; r < 4; ++r) {
            const int a = wp*16 + lg*4 + r;
            if (a < AA)
                Mb[(size_t)(n*AA + a)*DD + k0 + ln] = f2bf(acc[r]);
        }
    }
    // signal M-chunk (and c3) done
    __threadfence();
    __syncthreads();
    if (t == 0)
        __hip_atomic_store(&m2[blk], MAGICW, __ATOMIC_RELEASE, __HIP_MEMORY_SCOPE_AGENT);

    if (blk >= 288) return;            // 288 gemm tiles (BM=128)

    // ===================== Phase C (gemm) =====================
    const int bt = blk & 31, jt = blk >> 5;
    const int b0 = bt * GBM;
    const int j0 = jt * GBN;

    // wait: 16 conv slices (rows b0..b0+127 -> m1[bt*16..+16)) and
    //       heads nlo..nhi fully M-complete (m2[n*16..+16) each)
    {
        const int nlo = j0 / AA, nhi = (j0 + 63) / AA;
        const int cnt = 16 + (nhi - nlo + 1) * 16;
        if (t < cnt) {
            unsigned* wptr;
            if (t < 16) wptr = &m1[bt*16 + t];
            else {
                const int i = t - 16;
                wptr = &m2[(nlo + (i >> 4))*16 + (i & 15)];
            }
            while (__hip_atomic_load(wptr, __ATOMIC_ACQUIRE,
                                     __HIP_MEMORY_SCOPE_AGENT) != MAGICW)
                __builtin_amdgcn_s_sleep(1);
        }
    }
    __syncthreads();

    {
        unsigned short* xs = sbuf;                    // 16 KB
        unsigned short* ms = sbuf + GBM*GBK;          //  8 KB

        const int w    = t >> 6;
        const int lane = t & 63;
        const int ln   = lane & 15, lg = lane >> 4;
        const int wm   = w >> 1,   wn = w & 1;

        f32x4 acc[4][2] = {};

        for (int kc = 0; kc < DD; kc += GBK) {
            #pragma unroll
            for (int it = 0; it < 4; ++it) {
                const int chunk = it*256 + t;
                const int row = chunk >> 3, slot = chunk & 7;
                const int4 v = *(const int4*)(Xb + (size_t)(b0 + row)*DD + kc + slot*8);
                *(int4*)(xs + row*GBK + ((slot ^ (row & 7)) * 8)) = v;
            }
            #pragma unroll
            for (int it = 0; it < 2; ++it) {
                const int chunk = it*256 + t;
                const int row = chunk >> 3, slot = chunk & 7;
                const int4 v = *(const int4*)(Mb + (size_t)(j0 + row)*DD + kc + slot*8);
                *(int4*)(ms + row*GBK + ((slot ^ (row & 7)) * 8)) = v;
            }
            __syncthreads();

            #pragma unroll
            for (int kk = 0; kk < 2; ++kk) {
                bf16x8 av[4], bv[2];
                #pragma unroll
                for (int mt = 0; mt < 4; ++mt) {
                    const int row  = 64*wm + 16*mt + ln;
                    const int slot = (4*kk + lg) ^ (row & 7);
                    av[mt] = *(const bf16x8*)(xs + row*GBK + slot*8);
                }
                #pragma unroll
                for (int nt = 0; nt < 2; ++nt) {
                    const int row  = 32*wn + 16*nt + ln;
                    const int slot = (4*kk + lg) ^ (row & 7);
                    bv[nt] = *(const bf16x8*)(ms + row*GBK + slot*8);
                }
                #pragma unroll
                for (int mt = 0; mt < 4; ++mt)
                    #pragma unroll
                    for (int nt = 0; nt < 2; ++nt)
                        acc[mt][nt] = __builtin_amdgcn_mfma_f32_16x16x32_bf16(
                            av[mt], bv[nt], acc[mt][nt], 0, 0, 0);
            }
            __syncthreads();
        }

        // C/D layout: col=lane&15, row=(lane>>4)*4+reg  [m89/m91]
        float c3v[2];
        #pragma unroll
        for (int nt = 0; nt < 2; ++nt) c3v[nt] = c3[j0 + 32*wn + 16*nt + ln];

        #pragma unroll
        for (int mt = 0; mt < 4; ++mt)
            #pragma unroll
            for (int nt = 0; nt < 2; ++nt) {
                const int j = j0 + 32*wn + 16*nt + ln;
                #pragma unroll
                for (int r = 0; r < 4; ++r) {
                    const int b = b0 + 64*wm + 16*mt + 4*lg + r;
                    out[(size_t)b*JJ + j] = acc[mt][nt][r] + c3v[nt];
                }
            }
    }
}

// ---------------------------------------------------------------------------
extern "C" void kernel_launch(void* const* d_in, const int* in_sizes, int n_in,
                              void* d_out, int out_size, void* d_ws, size_t ws_size,
                              hipStream_t stream)
{
    const float* x  = (const float*)d_in[0];
    const float* W1 = (const float*)d_in[1];
    const float* b1 = (const float*)d_in[2];
    const float* W2 = (const float*)d_in[3];
    const float* b2 = (const float*)d_in[4];
    const float* Wv = (const float*)d_in[5];
    const float* bv = (const float*)d_in[6];
    const float* Wa = (const float*)d_in[7];
    const float* ba = (const float*)d_in[8];
    float* out = (float*)d_out;
    float* ws  = (float*)d_ws;

    // ws: c1[JJ] f32 | c3[JJ] f32 | Xb[BB*DD] u16 | Vb[JD] u16 | Mb[JD] u16
    //   | m1[512] u32 | m2[512] u32
    float* c1 = ws;
    float* c3 = c1 + JJ;
    unsigned short* Xb = (unsigned short*)(c3 + JJ);
    unsigned short* Vb = Xb + (size_t)BB*DD;
    unsigned short* Mb = Vb + (size_t)JD;
    unsigned* m1 = (unsigned*)(Mb + (size_t)JD);
    unsigned* m2 = m1 + 512;

    k_all<<<dim3(512), dim3(256), 0, stream>>>(
        x, W1, b1, W2, b2, Wv, bv, Wa, ba, out,
        Xb, Vb, Mb, c1, c3, m1, m2);
}

// Round 14
// 36.095 us; speedup vs baseline: 4.7857x; 4.7857x over previous
//
#include <hip/hip_runtime.h>
#include <hip/hip_bf16.h>

#define DD   512
#define NH   32
#define AA   18
#define JJ   (NH*AA)          // 576
#define BB   4096
#define JD   (JJ*DD)          // 294912

typedef short bf16x8 __attribute__((ext_vector_type(8)));
typedef float f32x4  __attribute__((ext_vector_type(4)));

static __device__ inline unsigned short f2bf(float f) {
    unsigned int x = __float_as_uint(f);
    unsigned int r = (x + 0x7fffu + ((x >> 16) & 1u)) >> 16;   // RNE
    return (unsigned short)r;
}
static __device__ inline float bf2f(unsigned short bits) {
    return __uint_as_float((unsigned int)bits << 16);
}

// ---------------------------------------------------------------------------
// K1 (R12 body; kt-loop unroll 2 -> 4): per (dc,n):
//  a) convert a private 4096-float slice of x -> bf16
//  b) stage U[a,e] = Wv + Wa - mean(Wa) as bf16, XOR-swizzled LDS;
//     dc==0 blocks also fold c1[j] = sum_e U[j,e]*b2[n,e]
//  c) V[n*18+a, d0..d0+32) = sum_e U[a,e] * W2[n,e,d]  via 16x16x32 MFMA.
//     grid (16 dc x 32 n) = 512 blocks, 256 thr (4 waves), LDS 32.3 KB.
// ---------------------------------------------------------------------------
__global__ __launch_bounds__(256) void k_V(
    const float* __restrict__ x, unsigned short* __restrict__ Xb,
    const float* __restrict__ W2, const float* __restrict__ Wv,
    const float* __restrict__ Wa, const float* __restrict__ b2,
    unsigned short* __restrict__ Vb, float* __restrict__ c1)
{
    const int t  = threadIdx.x;
    const int dc = blockIdx.x;          // 0..15
    const int n  = blockIdx.y;          // 0..31

    __shared__ __align__(16) unsigned short usb[32 * DD];   // 32 KB bf16
    __shared__ float redc[AA * 4];

    // --- a) convX slice: block bid owns float4s [bid*1024, bid*1024+1024)
    {
        const int bid = n*16 + dc;
        const float4* xin = (const float4*)x + (size_t)bid*1024;
        ushort4*      xo  = (ushort4*)Xb + (size_t)bid*1024;
        #pragma unroll
        for (int i = 0; i < 4; ++i) {
            const float4 v = xin[t + 256*i];
            ushort4 o;
            o.x = f2bf(v.x); o.y = f2bf(v.y); o.z = f2bf(v.z); o.w = f2bf(v.w);
            xo[t + 256*i] = o;
        }
    }

    // --- b) stage U (thread owns e = 2t, 2t+1), swizzled bf16 pair-writes
    {
        const int e = 2*t;
        float u0[AA], u1[AA];
        float msum0 = 0.f, msum1 = 0.f;
        #pragma unroll
        for (int a = 0; a < AA; ++a) {
            const float2 w = *(const float2*)(Wa + (size_t)(n*AA + a)*DD + e);
            u0[a] = w.x; u1[a] = w.y; msum0 += w.x; msum1 += w.y;
        }
        msum0 *= (1.0f/18.0f); msum1 *= (1.0f/18.0f);
        const float2 wv  = *(const float2*)(Wv + (size_t)n*DD + e);
        const float2 b2v = *(const float2*)(b2 + (size_t)n*DD + e);
        float p[AA];
        #pragma unroll
        for (int a = 0; a < AA; ++a) {
            u0[a] = wv.x + u0[a] - msum0;
            u1[a] = wv.y + u1[a] - msum1;
            const unsigned int pk = ((unsigned int)f2bf(u1[a]) << 16) | f2bf(u0[a]);
            const int slot = (t >> 2) ^ (a & 7);          // 16B-slot swizzle
            *(unsigned int*)(usb + a*DD + slot*8 + (t & 3)*2) = pk;
            p[a] = u0[a]*b2v.x + u1[a]*b2v.y;
        }
        if (dc == 0) {   // c1 fold (R5-validated reduce)
            #pragma unroll
            for (int a = 0; a < AA; ++a)
                for (int o = 32; o; o >>= 1) p[a] += __shfl_xor(p[a], o, 64);
            if ((t & 63) == 0) {
                const int w = t >> 6;
                #pragma unroll
                for (int a = 0; a < AA; ++a) redc[a*4 + w] = p[a];
            }
            __syncthreads();
            if (t < AA)
                c1[n*AA + t] = redc[t*4] + redc[t*4+1] + redc[t*4+2] + redc[t*4+3];
        }
    }
    __syncthreads();

    // --- c) MFMA contraction
    const int lane = t & 63, w = t >> 6;
    const int wp = w & 1;                 // a-tile (0: a 0..15, 1: a 16..17+pad)
    const int wd = w >> 1;                // d-sub-tile
    const int ln = lane & 15, lg = lane >> 4;
    const int d0 = dc*32 + wd*16;
    const int arow = wp*16 + ln;
    const float* w2base = W2 + (size_t)n*DD*DD + d0 + ln;

    f32x4 acc = {};
    #pragma unroll 4
    for (int kt = 0; kt < 16; ++kt) {
        const float* gp = w2base + (size_t)(kt*32 + lg*8)*DD;
        float wvv[8];
        #pragma unroll
        for (int j = 0; j < 8; ++j) wvv[j] = gp[(size_t)j*DD];
        bf16x8 bfrag;
        #pragma unroll
        for (int j = 0; j < 8; ++j) bfrag[j] = (short)f2bf(wvv[j]);
        const int slot = (kt*4 + lg) ^ (arow & 7);
        const bf16x8 afrag = *(const bf16x8*)(usb + arow*DD + slot*8);
        acc = __builtin_amdgcn_mfma_f32_16x16x32_bf16(afrag, bfrag, acc, 0, 0, 0);
    }

    // D layout: col=lane&15 (d), row=(lane>>4)*4+reg (a)   [m89/m91]
    #pragma unroll
    for (int r = 0; r < 4; ++r) {
        const int a = wp*16 + lg*4 + r;
        if (a < AA)
            Vb[(size_t)(n*AA + a)*DD + d0 + ln] = f2bf(acc[r]);
    }
}

// ---------------------------------------------------------------------------
// K2 (R12 body; kt-loop unroll 2 -> 4): per (kc,n):
//  a) kc==0: c3[j] = c1[j] + sum_d V[j,d]*b1[n,d] + bv[n] + ba[j] - mean(ba)
//  b) M[n*18+a, k0..k0+32) = sum_d V[a,d] * W1[n*512+d, k] -> bf16 (MFMA)
// ---------------------------------------------------------------------------
__global__ __launch_bounds__(256) void k_M(
    const float* __restrict__ W1, const unsigned short* __restrict__ Vb,
    const float* __restrict__ b1, const float* __restrict__ bv,
    const float* __restrict__ ba, const float* __restrict__ c1,
    unsigned short* __restrict__ Mb, float* __restrict__ c3)
{
    const int t  = threadIdx.x;
    const int kc = blockIdx.x;          // 0..15
    const int n  = blockIdx.y;          // 0..31

    __shared__ __align__(16) unsigned short vsb[32 * DD];   // 32 KB bf16
    __shared__ float redc[AA * 4];

    // stage V -> LDS swizzled (b128 both sides)
    for (int idx = t; idx < AA*64; idx += 256) {
        const int row = idx >> 6, slot = idx & 63;
        const int4 v = *(const int4*)(Vb + (size_t)(n*AA + row)*DD + slot*8);
        *(int4*)(vsb + row*DD + ((slot ^ (row & 7))*8)) = v;
    }
    __syncthreads();

    // --- a) c3 on kc==0 blocks (reads Vb global, pairwise)
    if (kc == 0) {
        const int e = 2*t;
        const float2 b1v = *(const float2*)(b1 + (size_t)n*DD + e);
        float p[AA];
        #pragma unroll
        for (int a = 0; a < AA; ++a) {
            const unsigned int pk = *(const unsigned int*)(Vb + (size_t)(n*AA + a)*DD + e);
            p[a] = bf2f((unsigned short)(pk & 0xffffu))*b1v.x
                 + bf2f((unsigned short)(pk >> 16))*b1v.y;
        }
        #pragma unroll
        for (int a = 0; a < AA; ++a)
            for (int o = 32; o; o >>= 1) p[a] += __shfl_xor(p[a], o, 64);
        if ((t & 63) == 0) {
            const int w = t >> 6;
            #pragma unroll
            for (int a = 0; a < AA; ++a) redc[a*4 + w] = p[a];
        }
        __syncthreads();
        if (t < AA) {
            float bam = 0.f;
            #pragma unroll
            for (int a = 0; a < AA; ++a) bam += ba[n*AA + a];
            c3[n*AA + t] = c1[n*AA + t]
                         + redc[t*4] + redc[t*4+1] + redc[t*4+2] + redc[t*4+3]
                         + bv[n] + ba[n*AA + t] - bam * (1.0f/18.0f);
        }
    }

    // --- b) MFMA contraction over d
    const int lane = t & 63, w = t >> 6;
    const int wp = w & 1;
    const int wd = w >> 1;
    const int ln = lane & 15, lg = lane >> 4;
    const int k0 = kc*32 + wd*16;
    const int arow = wp*16 + ln;
    const float* w1base = W1 + (size_t)n*DD*DD + k0 + ln;

    f32x4 acc = {};
    #pragma unroll 4
    for (int kt = 0; kt < 16; ++kt) {
        const float* gp = w1base + (size_t)(kt*32 + lg*8)*DD;
        float wvv[8];
        #pragma unroll
        for (int j = 0; j < 8; ++j) wvv[j] = gp[(size_t)j*DD];
        bf16x8 bfrag;
        #pragma unroll
        for (int j = 0; j < 8; ++j) bfrag[j] = (short)f2bf(wvv[j]);
        const int slot = (kt*4 + lg) ^ (arow & 7);
        const bf16x8 afrag = *(const bf16x8*)(vsb + arow*DD + slot*8);
        acc = __builtin_amdgcn_mfma_f32_16x16x32_bf16(afrag, bfrag, acc, 0, 0, 0);
    }

    #pragma unroll
    for (int r = 0; r < 4; ++r) {
        const int a = wp*16 + lg*4 + r;
        if (a < AA)
            Mb[(size_t)(n*AA + a)*DD + k0 + ln] = f2bf(acc[r]);
    }
}

// ---------------------------------------------------------------------------
// K3: out[b,j] = sum_k Xb[b,k]*Mb[j,k] + c3[j]   (bf16 MFMA)
//     EXACT R12 kernel: BM=128 BN=64 BK=64, 4 waves, XOR-swizzled LDS
//     (SQ_LDS_BANK_CONFLICT == 0 measured).
// ---------------------------------------------------------------------------
#define GBM 128
#define GBN 64
#define GBK 64

__global__ __launch_bounds__(256) void k_gemm(
    const unsigned short* __restrict__ Xb,   // [4096][512] bf16 bits
    const unsigned short* __restrict__ Mb,   // [576][512]  bf16 bits
    const float* __restrict__ c3, float* __restrict__ out)
{
    __shared__ __align__(16) unsigned short xs[GBM * GBK];   // 16 KB
    __shared__ __align__(16) unsigned short ms[GBN * GBK];   //  8 KB

    const int t    = threadIdx.x;
    const int w    = t >> 6;
    const int lane = t & 63;
    const int ln   = lane & 15, lg = lane >> 4;
    const int wm   = w >> 1,   wn = w & 1;
    const int b0 = blockIdx.x * GBM;
    const int j0 = blockIdx.y * GBN;

    f32x4 acc[4][2] = {};

    for (int kc = 0; kc < DD; kc += GBK) {
        #pragma unroll
        for (int it = 0; it < 4; ++it) {
            const int chunk = it*256 + t;
            const int row = chunk >> 3, slot = chunk & 7;
            const int4 v = *(const int4*)(Xb + (size_t)(b0 + row)*DD + kc + slot*8);
            *(int4*)(xs + row*GBK + ((slot ^ (row & 7)) * 8)) = v;
        }
        #pragma unroll
        for (int it = 0; it < 2; ++it) {
            const int chunk = it*256 + t;
            const int row = chunk >> 3, slot = chunk & 7;
            const int4 v = *(const int4*)(Mb + (size_t)(j0 + row)*DD + kc + slot*8);
            *(int4*)(ms + row*GBK + ((slot ^ (row & 7)) * 8)) = v;
        }
        __syncthreads();

        #pragma unroll
        for (int kk = 0; kk < 2; ++kk) {
            bf16x8 av[4], bv[2];
            #pragma unroll
            for (int mt = 0; mt < 4; ++mt) {
                const int row  = 64*wm + 16*mt + ln;
                const int slot = (4*kk + lg) ^ (row & 7);
                av[mt] = *(const bf16x8*)(xs + row*GBK + slot*8);
            }
            #pragma unroll
            for (int nt = 0; nt < 2; ++nt) {
                const int row  = 32*wn + 16*nt + ln;
                const int slot = (4*kk + lg) ^ (row & 7);
                bv[nt] = *(const bf16x8*)(ms + row*GBK + slot*8);
            }
            #pragma unroll
            for (int mt = 0; mt < 4; ++mt)
                #pragma unroll
                for (int nt = 0; nt < 2; ++nt)
                    acc[mt][nt] = __builtin_amdgcn_mfma_f32_16x16x32_bf16(
                        av[mt], bv[nt], acc[mt][nt], 0, 0, 0);
        }
        __syncthreads();
    }

    // C/D layout: col=lane&15, row=(lane>>4)*4+reg  [m89/m91]
    float c3v[2];
    #pragma unroll
    for (int nt = 0; nt < 2; ++nt) c3v[nt] = c3[j0 + 32*wn + 16*nt + ln];

    #pragma unroll
    for (int mt = 0; mt < 4; ++mt)
        #pragma unroll
        for (int nt = 0; nt < 2; ++nt) {
            const int j = j0 + 32*wn + 16*nt + ln;
            #pragma unroll
            for (int r = 0; r < 4; ++r) {
                const int b = b0 + 64*wm + 16*mt + 4*lg + r;
                out[(size_t)b*JJ + j] = acc[mt][nt][r] + c3v[nt];
            }
        }
}

// ---------------------------------------------------------------------------
extern "C" void kernel_launch(void* const* d_in, const int* in_sizes, int n_in,
                              void* d_out, int out_size, void* d_ws, size_t ws_size,
                              hipStream_t stream)
{
    const float* x  = (const float*)d_in[0];
    const float* W1 = (const float*)d_in[1];
    const float* b1 = (const float*)d_in[2];
    const float* W2 = (const float*)d_in[3];
    const float* b2 = (const float*)d_in[4];
    const float* Wv = (const float*)d_in[5];
    const float* bv = (const float*)d_in[6];
    const float* Wa = (const float*)d_in[7];
    const float* ba = (const float*)d_in[8];
    float* out = (float*)d_out;
    float* ws  = (float*)d_ws;

    // workspace: c1[JJ] f32 | c3[JJ] f32 | Xb[BB*DD] bf16 | Vb[JD] | Mb[JD]
    float* c1 = ws;
    float* c3 = c1 + JJ;
    unsigned short* Xb = (unsigned short*)(c3 + JJ);
    unsigned short* Vb = Xb + (size_t)BB*DD;
    unsigned short* Mb = Vb + (size_t)JD;

    k_V   <<<dim3(16, NH), 256, 0, stream>>>(x, Xb, W2, Wv, Wa, b2, Vb, c1);
    k_M   <<<dim3(16, NH), 256, 0, stream>>>(W1, Vb, b1, bv, ba, c1, Mb, c3);
    k_gemm<<<dim3(BB/GBM, JJ/GBN), 256, 0, stream>>>(Xb, Mb, c3, out);
}